// Round 11
// baseline (335.061 us; speedup 1.0000x reference)
//
#include <hip/hip_runtime.h>
#include <math.h>

#define NF 40
#define FS 401
#define AST 424            // A row stride (f16), 848B, 16B-aligned rows
#define PSTRIDE 160
#define BB 8
#define LL 160000
#define TOUT 1000
#define NTILE 512          // conv positions per block (4 waves x 128)
#define NCHUNKC 313        // 313*512 = 160256 >= 160000
#define ROWCH 121          // slab chunk stride per row; 121 % 8 == 1
#define ROWST (ROWCH*8)    // 968 f16 per row
#define EROW 520           // e-LDS row stride (f16)
#define WROW 402           // win table row stride (f32), [401]=0
#define TAUC 125           // taus per tail chunk (8 x 125 = 1000)
#define ECH (TAUC*PSTRIDE + 408)   // 20408 f16 staged per chunk (div by 8)

typedef __attribute__((ext_vector_type(8))) _Float16 half8v;
typedef __attribute__((ext_vector_type(4))) _Float16 half4v;
typedef __attribute__((ext_vector_type(2))) _Float16 half2v;
typedef __attribute__((ext_vector_type(4))) float float4v;
typedef _Float16 f16;

__device__ __forceinline__ float sigm(float x) { return 1.0f / (1.0f + __expf(-x)); }
__device__ __forceinline__ float tanh_fast(float x) { return 1.0f - 2.0f / (__expf(2.0f * x) + 1.0f); }

// ---------- prep (tiny): Gabor filters + win table ----------
__global__ __launch_bounds__(256) void prep_small(
    const float* __restrict__ cf_, const float* __restrict__ bw_,
    const float* __restrict__ pw_, f16* __restrict__ Ag, float* __restrict__ winG)
{
    const float PI_F = 3.14159265358979323846f;
    int blk = blockIdx.x;
    if (blk < 80) {
        int row = blk;
        int f = row >> 1, comp = row & 1;
        float Z = sqrtf(2.0f * logf(2.0f)) / PI_F;
        float cf = fminf(fmaxf(cf_[f], 0.0f), PI_F);
        float bw = fminf(fmaxf(bw_[f], 4.0f * Z), 401.0f * Z);
        float denom = 1.0f / (sqrtf(2.0f * PI_F) * bw);
        float inv2 = 1.0f / (2.0f * bw * bw);
        for (int k = threadIdx.x; k < AST; k += 256) {
            float v = 0.0f;
            if (k < FS) {
                float t = (float)(k - 200);
                float g = denom * expf(-(t * t) * inv2);
                float sv, cv;
                sincosf(cf * t, &sv, &cv);
                v = comp ? g * sv : g * cv;
            }
            Ag[row * AST + k] = (f16)v;
        }
        return;
    }
    int f = blk - 80;
    float pw = fminf(fmaxf(pw_[f], 2.0f / 401.0f), 0.5f);
    float invpw = 1.0f / pw;
    for (int j = threadIdx.x; j < WROW; j += 256) {
        float w = 0.0f;
        if (j < FS) {
            float tt = (float)j * (1.0f / 400.0f) - 0.5f;
            float u = tt * invpw;
            w = expf(-0.5f * u * u);
        }
        winG[f * WROW + j] = w;
    }
}

// ---------- conv via MFMA: direct f32 x read, N=128/wave, Toeplitz rotation ----------
__global__ __launch_bounds__(256, 2) void conv_mfma(
    const float* __restrict__ x,   // [BB][LL] f32 (original input)
    const f16* __restrict__ Ag,    // [80][AST]
    f16* __restrict__ eb)          // [nb][NF][LL]
{
    __shared__ __align__(16) unsigned char smem[40 * EROW * 2];
    f16* slab = (f16*)smem;
    f16* eL   = (f16*)smem;

    int chunk = blockIdx.x;
    int bi = blockIdx.y;
    int p0 = chunk * NTILE;
    int pbase = p0 - 200;                     // ≡ 0 (mod 8), may be negative
    const float* xs = x + (size_t)bi * LL;
    int tid = threadIdx.x;

    // build slab from f32: m-chunk loads 16 floats, emits 8 shifted-row windows
    for (int m = tid; m < 120; m += 256) {
        int g0 = pbase + 8 * m;
        float fv[16];
        if (g0 >= 0 && g0 + 16 <= LL) {
            float4 A = *(const float4*)(xs + g0);
            float4 Bv = *(const float4*)(xs + g0 + 4);
            float4 C = *(const float4*)(xs + g0 + 8);
            float4 D = *(const float4*)(xs + g0 + 12);
            fv[0]=A.x; fv[1]=A.y; fv[2]=A.z; fv[3]=A.w;
            fv[4]=Bv.x; fv[5]=Bv.y; fv[6]=Bv.z; fv[7]=Bv.w;
            fv[8]=C.x; fv[9]=C.y; fv[10]=C.z; fv[11]=C.w;
            fv[12]=D.x; fv[13]=D.y; fv[14]=D.z; fv[15]=D.w;
        } else {
#pragma unroll
            for (int j = 0; j < 16; ++j) {
                int gi = g0 + j;
                fv[j] = (gi >= 0 && gi < LL) ? xs[gi] : 0.0f;
            }
        }
        uint d[8];
#pragma unroll
        for (int j = 0; j < 8; ++j) {
            union { half2v h; uint u; } cv;
            cv.h[0] = (f16)fv[2 * j];
            cv.h[1] = (f16)fv[2 * j + 1];
            d[j] = cv.u;
        }
#pragma unroll
        for (int r = 0; r < 8; r += 2) {
            int b = r >> 1;
            *(uint4*)(&slab[r * ROWST + 8 * m]) = make_uint4(d[b], d[b+1], d[b+2], d[b+3]);
        }
#pragma unroll
        for (int r = 1; r < 8; r += 2) {
            int b = (r - 1) >> 1;
            uint4 w;
            w.x = __builtin_amdgcn_alignbyte(d[b+1], d[b],   2);
            w.y = __builtin_amdgcn_alignbyte(d[b+2], d[b+1], 2);
            w.z = __builtin_amdgcn_alignbyte(d[b+3], d[b+2], 2);
            w.w = __builtin_amdgcn_alignbyte(d[b+4], d[b+3], 2);
            *(uint4*)(&slab[r * ROWST + 8 * m]) = w;
        }
    }
    __syncthreads();

    int wv = tid >> 6, lane = tid & 63, q = lane >> 4, l15 = lane & 15;

    float4v acc[5][8];
#pragma unroll
    for (int t = 0; t < 5; ++t)
#pragma unroll
        for (int s = 0; s < 8; ++s)
            acc[t][s] = (float4v){0.f, 0.f, 0.f, 0.f};

    const f16* aP[5];
    const f16* bPtr[10];
#pragma unroll
    for (int t = 0; t < 5; ++t) aP[t] = Ag + (16 * t + l15) * AST + 8 * q;
#pragma unroll
    for (int s = 0; s < 10; ++s) {
        int pos = 128 * wv + 16 * s + l15;
        bPtr[s] = slab + (pos & 7) * ROWST + 8 * ((pos >> 3) + q);
    }

    half8v bf[8];
#pragma unroll
    for (int s = 0; s < 8; ++s) bf[s] = *(const half8v*)(bPtr[s]);

#pragma unroll
    for (int kk = 0; kk < 13; ++kk) {
        int k = 32 * kk;
        half8v af[5];
#pragma unroll
        for (int t = 0; t < 5; ++t) af[t] = *(const half8v*)(aP[t] + k);
        half8v nb0, nb1;
        if (kk < 12) {
            nb0 = *(const half8v*)(bPtr[8] + k);
            nb1 = *(const half8v*)(bPtr[9] + k);
        }
#pragma unroll
        for (int t = 0; t < 5; ++t)
#pragma unroll
            for (int s = 0; s < 8; ++s)
                acc[t][s] = __builtin_amdgcn_mfma_f32_16x16x32_f16(af[t], bf[s], acc[t][s], 0, 0, 0);
        if (kk < 12) {
#pragma unroll
            for (int s = 0; s < 6; ++s) bf[s] = bf[s + 2];
            bf[6] = nb0; bf[7] = nb1;
        }
    }

    __syncthreads();

#pragma unroll
    for (int t = 0; t < 5; ++t) {
        int f0 = 8 * t + 2 * q;
#pragma unroll
        for (int s = 0; s < 8; ++s) {
            float4v a = acc[t][s];
            int pl = 128 * wv + 16 * s + l15;
            eL[f0 * EROW + pl] = (f16)(a.x * a.x + a.y * a.y);
            eL[(f0 + 1) * EROW + pl] = (f16)(a.z * a.z + a.w * a.w);
        }
    }
    __syncthreads();

    f16* ebb = eb + (size_t)bi * NF * LL;
#pragma unroll
    for (int it = 0; it < 10; ++it) {
        int idx = it * 256 + tid;
        int row = idx >> 6;
        int off = (idx & 63) * 8;
        if (p0 + off < LL) {
            uint4 v = *(const uint4*)(&eL[row * EROW + off]);
            *(uint4*)(&ebb[row * LL + p0 + off]) = v;
        }
    }
}

// ---------- fused tail: pool + scan + GRU-PCEN, one block per (bi, f), 512 thr ----------
__global__ __launch_bounds__(512, 2) void tail_kernel(
    const f16* __restrict__ eb,     // [nb][NF][LL]
    const float* __restrict__ winG, // [NF][WROW]
    const float* __restrict__ w_ih, const float* __restrict__ w_hh,
    const float* __restrict__ b_ih, const float* __restrict__ b_hh,
    const float* __restrict__ hw1, const float* __restrict__ hb1,
    const float* __restrict__ hw2, const float* __restrict__ hb2,
    float* __restrict__ out)        // [nb][NF][TOUT]
{
    __shared__ __align__(16) float win[416];
    __shared__ __align__(16) float xsh[1024];
    __shared__ __align__(16) float msh[1024];
    __shared__ f16 s_whhA[96 * 40];
    __shared__ f16 s_w1A[32 * 40];
    __shared__ __align__(16) float4 s_A1[32];
    __shared__ __align__(16) float4 s_A2[32];
    __shared__ float s_hb1[32];
    __shared__ float s_hw2[64];
    __shared__ float s_hb2[2];
    __shared__ __align__(16) unsigned char ureg[ECH * 2];  // es overlay sh1/sh2
    f16* es = (f16*)ureg;

    int f = blockIdx.x;
    int bi = blockIdx.y;
    int tid = threadIdx.x;

    for (int i = tid; i < 96 * 32; i += 512) {
        int m = i >> 5, k = i & 31;
        s_whhA[m * 40 + k] = (f16)w_hh[i];
    }
    for (int i = tid; i < 32 * 32; i += 512) {
        int m = i >> 5, k = i & 31;
        s_w1A[m * 40 + k] = (f16)hw1[i];
    }
    if (tid < 32) {
        int j = tid;
        s_A1[j] = make_float4(w_ih[j], b_ih[j] + b_hh[j],
                              w_ih[32 + j], b_ih[32 + j] + b_hh[32 + j]);
        s_A2[j] = make_float4(w_ih[64 + j], b_ih[64 + j], b_hh[64 + j], 0.0f);
        s_hb1[j] = hb1[j];
    }
    if (tid < 64) s_hw2[tid] = hw2[tid];
    if (tid < 2)  s_hb2[tid] = hb2[tid];
    if (tid < 416) win[tid] = (tid < WROW) ? winG[f * WROW + tid] : 0.0f;
    if (tid >= 488) { int i = 512 + tid; xsh[i] = 0.0f; msh[i] = 0.0f; }
    __syncthreads();

    // ---- phase 1: pooling, 8 chunks of 125 taus ----
    const f16* erow = eb + ((size_t)bi * NF + f) * LL;
    int ft = tid >> 4, l16 = tid & 15;    // 32 frames per pass
    for (int c = 0; c < 8; ++c) {
        int start = c * (TAUC * PSTRIDE) - 200;   // ≡ 0 (mod 8)
        if (c > 0 && c < 7) {
            for (int j = tid; j < ECH / 8; j += 512)
                *(uint4*)(&es[8 * j]) = *(const uint4*)(erow + start + 8 * j);
        } else {
            for (int j = tid; j < ECH; j += 512) {
                int p = start + j;
                es[j] = (p >= 0 && p < LL) ? erow[p] : (f16)0.0f;
            }
        }
        __syncthreads();
#pragma unroll
        for (int pass = 0; pass < 4; ++pass) {
            int tauL = pass * 32 + ft;
            if (tauL < TAUC) {
                int base = tauL * PSTRIDE;
                float acc = 0.0f;
#pragma unroll
                for (int m = 0; m < 13; ++m) {
                    int kw = 2 * l16 + 32 * m;
                    half2v ep = *(const half2v*)(&es[base + kw]);
                    float2 wp = *(const float2*)(&win[kw]);
                    acc = fmaf((float)ep[0], wp.x, acc);
                    acc = fmaf((float)ep[1], wp.y, acc);
                }
#pragma unroll
                for (int off = 8; off > 0; off >>= 1)
                    acc += __shfl_down(acc, off, 16);
                if (l16 == 0) xsh[c * TAUC + tauL] = acc;
            }
        }
        __syncthreads();
    }

    // ---- phase 2: decayed scan (wave 0), xsh -> msh ----
    if (tid < 64) {
        int lane = tid;
        const float a1 = 0.96f;
        const float a2 = a1 * a1, a4 = a2 * a2, a8 = a4 * a4;
        const float a16 = a8 * a8, a32 = a16 * a16;
        float al1 = powf(a1, (float)(lane + 1));
        float carry = 0.0f;
        for (int c = 0; c < TOUT; c += 64) {
            float y = 0.04f * xsh[c + lane];
            float u;
            u = __shfl_up(y, 1, 64);  if (lane >= 1)  y = fmaf(a1, u, y);
            u = __shfl_up(y, 2, 64);  if (lane >= 2)  y = fmaf(a2, u, y);
            u = __shfl_up(y, 4, 64);  if (lane >= 4)  y = fmaf(a4, u, y);
            u = __shfl_up(y, 8, 64);  if (lane >= 8)  y = fmaf(a8, u, y);
            u = __shfl_up(y, 16, 64); if (lane >= 16) y = fmaf(a16, u, y);
            u = __shfl_up(y, 32, 64); if (lane >= 32) y = fmaf(a32, u, y);
            y = fmaf(al1, carry, y);
            carry = __shfl(y, 63, 64);
            msh[c + lane] = y;
        }
    }
    __syncthreads();

    // ---- phase 3: GRU + PCEN, 8 waves x 8 groups of 16 taus ----
    int wv = tid >> 6, lane = tid & 63;
    int c16 = lane & 15, q = lane >> 4;
    f16* sh1 = (f16*)(ureg + wv * 2560);
    f16* sh2 = (f16*)(ureg + wv * 2560 + 1280);
    float* outb = out + ((size_t)bi * NF + f) * TOUT;

#pragma unroll
    for (int g = 0; g < 8; ++g) {
        int t = (wv * 8 + g) * 16 + c16;          // 0..1023
        int tc = (t < TOUT) ? t : (TOUT - 1);
        float xc = xsh[tc];
        float xp = (tc == 0) ? xc : xsh[tc - 1];
        float mv = msh[tc];

        float h1v[8];
#pragma unroll
        for (int jj = 0; jj < 8; ++jj) {
            int j = (jj < 4) ? (4 * q + jj) : (16 + 4 * q + (jj - 4));
            float4 a1 = s_A1[j];
            float4 a2 = s_A2[j];
            float r = sigm(fmaf(xp, a1.x, a1.y));
            float z = sigm(fmaf(xp, a1.z, a1.w));
            float n = tanh_fast(fmaf(xp, a2.x, a2.y) + r * a2.z);
            h1v[jj] = (1.0f - z) * n;
        }
        {
            half4v lo = {(f16)h1v[0], (f16)h1v[1], (f16)h1v[2], (f16)h1v[3]};
            half4v hi = {(f16)h1v[4], (f16)h1v[5], (f16)h1v[6], (f16)h1v[7]};
            *(half4v*)(&sh1[c16 * 40 + 4 * q]) = lo;
            *(half4v*)(&sh1[c16 * 40 + 16 + 4 * q]) = hi;
        }
        float4v acc[6];
        {
            half8v bfv = *(const half8v*)(&sh1[c16 * 40 + 8 * q]);
#pragma unroll
            for (int tt = 0; tt < 6; ++tt) {
                half8v af = *(const half8v*)(&s_whhA[(16 * tt + c16) * 40 + 8 * q]);
                acc[tt] = __builtin_amdgcn_mfma_f32_16x16x32_f16(af, bfv, (float4v){0.f,0.f,0.f,0.f}, 0, 0, 0);
            }
        }
        float h2v[8];
#pragma unroll
        for (int jj = 0; jj < 8; ++jj) {
            int j = (jj < 4) ? (4 * q + jj) : (16 + 4 * q + (jj - 4));
            int reg = jj & 3;
            float accR = (jj < 4) ? acc[0][reg] : acc[1][reg];
            float accZ = (jj < 4) ? acc[2][reg] : acc[3][reg];
            float accN = (jj < 4) ? acc[4][reg] : acc[5][reg];
            float4 a1 = s_A1[j];
            float4 a2 = s_A2[j];
            float r = sigm(fmaf(xc, a1.x, a1.y) + accR);
            float z = sigm(fmaf(xc, a1.z, a1.w) + accZ);
            float gn = accN + a2.z;
            float n = tanh_fast(fmaf(xc, a2.x, a2.y) + r * gn);
            h2v[jj] = fmaf(z, h1v[jj] - n, n);
        }
        {
            half4v lo = {(f16)h2v[0], (f16)h2v[1], (f16)h2v[2], (f16)h2v[3]};
            half4v hi = {(f16)h2v[4], (f16)h2v[5], (f16)h2v[6], (f16)h2v[7]};
            *(half4v*)(&sh2[c16 * 40 + 4 * q]) = lo;
            *(half4v*)(&sh2[c16 * 40 + 16 + 4 * q]) = hi;
        }
        float4v hacc[2];
        {
            half8v bfv = *(const half8v*)(&sh2[c16 * 40 + 8 * q]);
#pragma unroll
            for (int tt = 0; tt < 2; ++tt) {
                half8v af = *(const half8v*)(&s_w1A[(16 * tt + c16) * 40 + 8 * q]);
                hacc[tt] = __builtin_amdgcn_mfma_f32_16x16x32_f16(af, bfv, (float4v){0.f,0.f,0.f,0.f}, 0, 0, 0);
            }
        }
        float p0 = 0.f, p1 = 0.f;
#pragma unroll
        for (int jj = 0; jj < 8; ++jj) {
            int i = (jj < 4) ? (4 * q + jj) : (16 + 4 * q + (jj - 4));
            int reg = jj & 3;
            float hv = (jj < 4) ? hacc[0][reg] : hacc[1][reg];
            hv = fmaxf(hv + s_hb1[i], 0.0f);
            p0 = fmaf(hv, s_hw2[i], p0);
            p1 = fmaf(hv, s_hw2[32 + i], p1);
        }
        p0 += __shfl_xor(p0, 16);
        p0 += __shfl_xor(p0, 32);
        p1 += __shfl_xor(p1, 16);
        p1 += __shfl_xor(p1, 32);

        float alpha = sigm(p0 + s_hb2[0]);
        float rr = fmaf(0.8f, sigm(p1 + s_hb2[1]), 0.2f);
        float md = __expf(alpha * __logf(mv + 1e-6f));
        float bse = xc / md + 2.0f;
        float val = __expf(rr * __logf(bse)) - __expf(rr * 0.69314718056f);
        if (q == 0 && t < TOUT)
            outb[t] = val;
    }
}

extern "C" void kernel_launch(void* const* d_in, const int* in_sizes, int n_in,
                              void* d_out, int out_size, void* d_ws, size_t ws_size,
                              hipStream_t stream) {
    const float* x    = (const float*)d_in[0];
    const float* cf   = (const float*)d_in[1];
    const float* bw   = (const float*)d_in[2];
    const float* pw   = (const float*)d_in[3];
    const float* w_ih = (const float*)d_in[4];
    const float* w_hh = (const float*)d_in[5];
    const float* b_ih = (const float*)d_in[6];
    const float* b_hh = (const float*)d_in[7];
    const float* hw1  = (const float*)d_in[8];
    const float* hb1  = (const float*)d_in[9];
    const float* hw2  = (const float*)d_in[10];
    const float* hb2  = (const float*)d_in[11];
    float* out = (float*)d_out;

    // tier: batches per conv slice by ws capacity (ws_size constant -> graph-safe)
    const size_t ag_b = (size_t)80 * AST * 2;
    const size_t wg_b = (size_t)NF * WROW * 4;
    size_t fixed = ag_b + wg_b;
    size_t e_per_batch = (size_t)NF * LL * 2;
    int nb;
    if (ws_size >= fixed + 8 * e_per_batch)      nb = 8;
    else if (ws_size >= fixed + 2 * e_per_batch) nb = 2;
    else                                         nb = 1;
    int nslice = BB / nb;

    f16* Ag     = (f16*)d_ws;                       // [80][AST]
    float* winG = (float*)(Ag + (size_t)80 * AST);  // [NF][WROW]
    f16* ebuf   = (f16*)(winG + (size_t)NF * WROW); // [nb][NF][LL]

    prep_small<<<dim3(120), dim3(256), 0, stream>>>(cf, bw, pw, Ag, winG);

    for (int sl = 0; sl < nslice; ++sl) {
        conv_mfma<<<dim3(NCHUNKC, nb), dim3(256), 0, stream>>>(
            x + (size_t)sl * nb * LL, Ag, ebuf);
        tail_kernel<<<dim3(NF, nb), dim3(512), 0, stream>>>(
            ebuf, winG, w_ih, w_hh, b_ih, b_hh, hw1, hb1, hw2, hb2,
            out + (size_t)sl * nb * NF * TOUT);
    }
}

// Round 12
// 279.350 us; speedup vs baseline: 1.1994x; 1.1994x over previous
//
#include <hip/hip_runtime.h>
#include <math.h>

#define NF 40
#define FS 401
#define AST 424            // A row stride (f16), 848B, 16B-aligned rows
#define PSTRIDE 160
#define BB 8
#define LL 160000
#define PADL 256
#define LST 161024         // PADL + LL + 768 pad; multiple of 256
#define TOUT 1000
#define NTILE 512          // conv positions per block (4 waves x 128)
#define NCHUNKC 313        // 313*512 = 160256 >= 160000
#define ROWCH 121          // slab chunk stride per row; 121 % 8 == 1
#define ROWST (ROWCH*8)    // 968 f16 per row
#define EROW 520           // e-LDS row stride (f16)
#define WROW 402           // win table row stride (f32), [401]=0
#define TCP 32             // frames per pool block
#define NCHUNKP 32         // 32*32 = 1024 >= 1000
#define PELEM (TCP*PSTRIDE + 408)   // 5528 staged f16 per pool block
#define NCONVB 5032        // BB*LST/256 exactly

typedef __attribute__((ext_vector_type(8))) _Float16 half8v;
typedef __attribute__((ext_vector_type(4))) _Float16 half4v;
typedef __attribute__((ext_vector_type(2))) _Float16 half2v;
typedef __attribute__((ext_vector_type(4))) float float4v;
typedef _Float16 f16;

__device__ __forceinline__ float sigm(float x) { return 1.0f / (1.0f + __expf(-x)); }
__device__ __forceinline__ float tanh_fast(float x) { return 1.0f - 2.0f / (__expf(2.0f * x) + 1.0f); }

// ---------- prep (single dispatch): x->f16 padded, Gabor filters, win table ----------
__global__ __launch_bounds__(256) void prep_all(
    const float* __restrict__ x, const float* __restrict__ cf_,
    const float* __restrict__ bw_, const float* __restrict__ pw_,
    f16* __restrict__ xb, f16* __restrict__ Ag, float* __restrict__ winG)
{
    int blk = blockIdx.x;
    if (blk < NCONVB) {
        int i = blk * 256 + threadIdx.x;
        int b = i / LST, o = i % LST;
        float v = 0.0f;
        if (o >= PADL && o < PADL + LL) v = x[b * LL + (o - PADL)];
        xb[i] = (f16)v;
        return;
    }
    const float PI_F = 3.14159265358979323846f;
    if (blk < NCONVB + 80) {
        int row = blk - NCONVB;
        int f = row >> 1, comp = row & 1;
        float Z = sqrtf(2.0f * logf(2.0f)) / PI_F;
        float cf = fminf(fmaxf(cf_[f], 0.0f), PI_F);
        float bw = fminf(fmaxf(bw_[f], 4.0f * Z), 401.0f * Z);
        float denom = 1.0f / (sqrtf(2.0f * PI_F) * bw);
        float inv2 = 1.0f / (2.0f * bw * bw);
        for (int k = threadIdx.x; k < AST; k += 256) {
            float v = 0.0f;
            if (k < FS) {
                float t = (float)(k - 200);
                float g = denom * expf(-(t * t) * inv2);
                float sv, cv;
                sincosf(cf * t, &sv, &cv);
                v = comp ? g * sv : g * cv;
            }
            Ag[row * AST + k] = (f16)v;
        }
        return;
    }
    int f = blk - NCONVB - 80;
    float pw = fminf(fmaxf(pw_[f], 2.0f / 401.0f), 0.5f);
    float invpw = 1.0f / pw;
    for (int j = threadIdx.x; j < WROW; j += 256) {
        float w = 0.0f;
        if (j < FS) {
            float tt = (float)j * (1.0f / 400.0f) - 0.5f;
            float u = tt * invpw;
            w = expf(-0.5f * u * u);
        }
        winG[f * WROW + j] = w;
    }
}

// ---------- conv via MFMA: N=128/wave + Toeplitz rotation + coalesced epilogue ----------
__global__ __launch_bounds__(256, 2) void conv_mfma(
    const f16* __restrict__ xb,    // padded [nb][LST]
    const f16* __restrict__ Ag,    // [80][AST]
    f16* __restrict__ eb)          // [nb][NF][LL]
{
    __shared__ __align__(16) unsigned char smem[40 * EROW * 2];
    f16* slab = (f16*)smem;
    f16* eL   = (f16*)smem;

    int chunk = blockIdx.x;
    int bi = blockIdx.y;
    int p0 = chunk * NTILE;
    int pbase = PADL + p0 - 200;              // ≡ 0 (mod 8)
    const f16* xs = xb + (size_t)bi * LST;
    int tid = threadIdx.x;

    for (int sc = tid; sc < 8 * 120; sc += 256) {
        int r = sc / 120, m = sc - r * 120;
        int s0 = pbase + 8 * m + (r & ~1);
        const uint* gp = (const uint*)(xs + s0);
        uint v0 = gp[0], v1 = gp[1], v2 = gp[2], v3 = gp[3], v4 = gp[4];
        if (r & 1) {
            v0 = __builtin_amdgcn_alignbyte(v1, v0, 2);
            v1 = __builtin_amdgcn_alignbyte(v2, v1, 2);
            v2 = __builtin_amdgcn_alignbyte(v3, v2, 2);
            v3 = __builtin_amdgcn_alignbyte(v4, v3, 2);
        }
        *(uint4*)(&slab[r * ROWST + 8 * m]) = make_uint4(v0, v1, v2, v3);
    }
    __syncthreads();

    int wv = tid >> 6, lane = tid & 63, q = lane >> 4, l15 = lane & 15;

    float4v acc[5][8];
#pragma unroll
    for (int t = 0; t < 5; ++t)
#pragma unroll
        for (int s = 0; s < 8; ++s)
            acc[t][s] = (float4v){0.f, 0.f, 0.f, 0.f};

    const f16* aP[5];
    const f16* bPtr[10];
#pragma unroll
    for (int t = 0; t < 5; ++t) aP[t] = Ag + (16 * t + l15) * AST + 8 * q;
#pragma unroll
    for (int s = 0; s < 10; ++s) {
        int pos = 128 * wv + 16 * s + l15;
        bPtr[s] = slab + (pos & 7) * ROWST + 8 * ((pos >> 3) + q);
    }

    half8v bf[8];
#pragma unroll
    for (int s = 0; s < 8; ++s) bf[s] = *(const half8v*)(bPtr[s]);

#pragma unroll
    for (int kk = 0; kk < 13; ++kk) {
        int k = 32 * kk;
        half8v af[5];
#pragma unroll
        for (int t = 0; t < 5; ++t) af[t] = *(const half8v*)(aP[t] + k);
        half8v nb0, nb1;
        if (kk < 12) {
            nb0 = *(const half8v*)(bPtr[8] + k);
            nb1 = *(const half8v*)(bPtr[9] + k);
        }
#pragma unroll
        for (int t = 0; t < 5; ++t)
#pragma unroll
            for (int s = 0; s < 8; ++s)
                acc[t][s] = __builtin_amdgcn_mfma_f32_16x16x32_f16(af[t], bf[s], acc[t][s], 0, 0, 0);
        if (kk < 12) {
#pragma unroll
            for (int s = 0; s < 6; ++s) bf[s] = bf[s + 2];
            bf[6] = nb0; bf[7] = nb1;
        }
    }

    __syncthreads();

#pragma unroll
    for (int t = 0; t < 5; ++t) {
        int f0 = 8 * t + 2 * q;
#pragma unroll
        for (int s = 0; s < 8; ++s) {
            float4v a = acc[t][s];
            int pl = 128 * wv + 16 * s + l15;
            eL[f0 * EROW + pl] = (f16)(a.x * a.x + a.y * a.y);
            eL[(f0 + 1) * EROW + pl] = (f16)(a.z * a.z + a.w * a.w);
        }
    }
    __syncthreads();

    f16* ebb = eb + (size_t)bi * NF * LL;
#pragma unroll
    for (int it = 0; it < 10; ++it) {
        int idx = it * 256 + tid;
        int row = idx >> 6;
        int off = (idx & 63) * 8;
        if (p0 + off < LL) {
            uint4 v = *(const uint4*)(&eL[row * EROW + off]);
            *(uint4*)(&ebb[row * LL + p0 + off]) = v;
        }
    }
}

// ---------- Gaussian pooling v2: f16 LDS staging, precomputed win ----------
__global__ __launch_bounds__(256) void pool_kernel(
    const f16* __restrict__ eb, const float* __restrict__ winG, float* __restrict__ Xout)
{
    __shared__ __align__(16) f16 es[PELEM + 8];
    __shared__ __align__(16) float win[416];
    int chunk = blockIdx.x;
    int f = blockIdx.y;
    int bi = blockIdx.z;
    int tau0 = chunk * TCP;
    int start = tau0 * PSTRIDE - 200;               // ≡ 0 (mod 8)
    int tid = threadIdx.x;

    for (int k = tid; k < 416; k += 256)
        win[k] = (k < WROW) ? winG[f * WROW + k] : 0.0f;

    const f16* erow = eb + ((size_t)bi * NF + f) * LL;
    if (start >= 0 && start + PELEM <= LL) {
        for (int j = tid; j < PELEM / 8; j += 256)
            *(uint4*)(&es[8 * j]) = *(const uint4*)(erow + start + 8 * j);
    } else {
        for (int j = tid; j < PELEM; j += 256) {
            int p = start + j;
            es[j] = (p >= 0 && p < LL) ? erow[p] : (f16)0.0f;
        }
    }
    __syncthreads();

    int ft = tid >> 4, l16 = tid & 15;
#pragma unroll
    for (int pass = 0; pass < 2; ++pass) {
        int frame = pass * 16 + ft;
        int base = frame * PSTRIDE;
        float acc = 0.0f;
#pragma unroll
        for (int m = 0; m < 13; ++m) {
            int kw = 2 * l16 + 32 * m;
            half2v ep = *(const half2v*)(&es[base + kw]);
            float2 wp = *(const float2*)(&win[kw]);
            acc = fmaf((float)ep[0], wp.x, acc);
            acc = fmaf((float)ep[1], wp.y, acc);
        }
#pragma unroll
        for (int off = 8; off > 0; off >>= 1)
            acc += __shfl_down(acc, off, 16);
        int tau = tau0 + frame;
        if (l16 == 0 && tau < TOUT)
            Xout[((size_t)bi * NF + f) * TOUT + tau] = acc;
    }
}

// ---------- fused scan + GRU-PCEN: one 256-thread block per (bi, f) bin ----------
__global__ __launch_bounds__(256) void scanctrl_kernel(
    const float* __restrict__ X,    // [nb][NF][TOUT]
    const float* __restrict__ w_ih, const float* __restrict__ w_hh,
    const float* __restrict__ b_ih, const float* __restrict__ b_hh,
    const float* __restrict__ hw1, const float* __restrict__ hb1,
    const float* __restrict__ hw2, const float* __restrict__ hb2,
    float* __restrict__ out)        // [nb][NF][TOUT]
{
    __shared__ __align__(16) float xsh[1024];
    __shared__ __align__(16) float msh[1024];
    __shared__ f16 s_whhA[96 * 40];
    __shared__ f16 s_w1A[32 * 40];
    __shared__ __align__(16) float4 s_A1[32];
    __shared__ __align__(16) float4 s_A2[32];
    __shared__ float s_hb1[32];
    __shared__ float s_hw2[64];
    __shared__ float s_hb2[2];
    __shared__ f16 sh1[4][16 * 40];
    __shared__ f16 sh2[4][16 * 40];

    int bin = blockIdx.x;
    int tid = threadIdx.x;
    const float* Xrow = X + (size_t)bin * TOUT;

    for (int i = tid; i < 96 * 32; i += 256) {
        int m = i >> 5, k = i & 31;
        s_whhA[m * 40 + k] = (f16)w_hh[i];
    }
    for (int i = tid; i < 32 * 32; i += 256) {
        int m = i >> 5, k = i & 31;
        s_w1A[m * 40 + k] = (f16)hw1[i];
    }
    if (tid < 32) {
        int j = tid;
        s_A1[j] = make_float4(w_ih[j], b_ih[j] + b_hh[j],
                              w_ih[32 + j], b_ih[32 + j] + b_hh[32 + j]);
        s_A2[j] = make_float4(w_ih[64 + j], b_ih[64 + j], b_hh[64 + j], 0.0f);
        s_hb1[j] = hb1[j];
    }
    if (tid < 64) s_hw2[tid] = hw2[tid];
    if (tid < 2)  s_hb2[tid] = hb2[tid];
    for (int i = tid; i < 1024; i += 256)
        xsh[i] = (i < TOUT) ? Xrow[i] : 0.0f;
    __syncthreads();

    // ---- decayed scan (wave 0), xsh -> msh ----
    if (tid < 64) {
        int lane = tid;
        const float a1 = 0.96f;
        const float a2 = a1 * a1, a4 = a2 * a2, a8 = a4 * a4;
        const float a16 = a8 * a8, a32 = a16 * a16;
        float al1 = powf(a1, (float)(lane + 1));
        float carry = 0.0f;
        for (int c = 0; c < TOUT; c += 64) {
            float y = 0.04f * xsh[c + lane];
            float u;
            u = __shfl_up(y, 1, 64);  if (lane >= 1)  y = fmaf(a1, u, y);
            u = __shfl_up(y, 2, 64);  if (lane >= 2)  y = fmaf(a2, u, y);
            u = __shfl_up(y, 4, 64);  if (lane >= 4)  y = fmaf(a4, u, y);
            u = __shfl_up(y, 8, 64);  if (lane >= 8)  y = fmaf(a8, u, y);
            u = __shfl_up(y, 16, 64); if (lane >= 16) y = fmaf(a16, u, y);
            u = __shfl_up(y, 32, 64); if (lane >= 32) y = fmaf(a32, u, y);
            y = fmaf(al1, carry, y);
            carry = __shfl(y, 63, 64);
            msh[c + lane] = y;
        }
    }
    __syncthreads();

    // ---- GRU controller + PCEN: 4 waves x 16 groups of 16 taus ----
    int wv = tid >> 6, lane = tid & 63;
    int c16 = lane & 15, q = lane >> 4;
    float* outb = out + (size_t)bin * TOUT;

#pragma unroll 2
    for (int g = 0; g < 16; ++g) {
        int t = (wv * 16 + g) * 16 + c16;         // 0..1023
        int tc = (t < TOUT) ? t : (TOUT - 1);
        float xc = xsh[tc];
        float xp = (tc == 0) ? xc : xsh[tc - 1];
        float mv = msh[tc];

        float h1v[8];
#pragma unroll
        for (int jj = 0; jj < 8; ++jj) {
            int j = (jj < 4) ? (4 * q + jj) : (16 + 4 * q + (jj - 4));
            float4 a1 = s_A1[j];
            float4 a2 = s_A2[j];
            float r = sigm(fmaf(xp, a1.x, a1.y));
            float z = sigm(fmaf(xp, a1.z, a1.w));
            float n = tanh_fast(fmaf(xp, a2.x, a2.y) + r * a2.z);
            h1v[jj] = (1.0f - z) * n;
        }
        {
            half4v lo = {(f16)h1v[0], (f16)h1v[1], (f16)h1v[2], (f16)h1v[3]};
            half4v hi = {(f16)h1v[4], (f16)h1v[5], (f16)h1v[6], (f16)h1v[7]};
            *(half4v*)(&sh1[wv][c16 * 40 + 4 * q]) = lo;
            *(half4v*)(&sh1[wv][c16 * 40 + 16 + 4 * q]) = hi;
        }
        float4v acc[6];
        {
            half8v bfv = *(const half8v*)(&sh1[wv][c16 * 40 + 8 * q]);
#pragma unroll
            for (int tt = 0; tt < 6; ++tt) {
                half8v af = *(const half8v*)(&s_whhA[(16 * tt + c16) * 40 + 8 * q]);
                acc[tt] = __builtin_amdgcn_mfma_f32_16x16x32_f16(af, bfv, (float4v){0.f,0.f,0.f,0.f}, 0, 0, 0);
            }
        }
        float h2v[8];
#pragma unroll
        for (int jj = 0; jj < 8; ++jj) {
            int j = (jj < 4) ? (4 * q + jj) : (16 + 4 * q + (jj - 4));
            int reg = jj & 3;
            float accR = (jj < 4) ? acc[0][reg] : acc[1][reg];
            float accZ = (jj < 4) ? acc[2][reg] : acc[3][reg];
            float accN = (jj < 4) ? acc[4][reg] : acc[5][reg];
            float4 a1 = s_A1[j];
            float4 a2 = s_A2[j];
            float r = sigm(fmaf(xc, a1.x, a1.y) + accR);
            float z = sigm(fmaf(xc, a1.z, a1.w) + accZ);
            float gn = accN + a2.z;
            float n = tanh_fast(fmaf(xc, a2.x, a2.y) + r * gn);
            h2v[jj] = fmaf(z, h1v[jj] - n, n);
        }
        {
            half4v lo = {(f16)h2v[0], (f16)h2v[1], (f16)h2v[2], (f16)h2v[3]};
            half4v hi = {(f16)h2v[4], (f16)h2v[5], (f16)h2v[6], (f16)h2v[7]};
            *(half4v*)(&sh2[wv][c16 * 40 + 4 * q]) = lo;
            *(half4v*)(&sh2[wv][c16 * 40 + 16 + 4 * q]) = hi;
        }
        float4v hacc[2];
        {
            half8v bfv = *(const half8v*)(&sh2[wv][c16 * 40 + 8 * q]);
#pragma unroll
            for (int tt = 0; tt < 2; ++tt) {
                half8v af = *(const half8v*)(&s_w1A[(16 * tt + c16) * 40 + 8 * q]);
                hacc[tt] = __builtin_amdgcn_mfma_f32_16x16x32_f16(af, bfv, (float4v){0.f,0.f,0.f,0.f}, 0, 0, 0);
            }
        }
        float p0 = 0.f, p1 = 0.f;
#pragma unroll
        for (int jj = 0; jj < 8; ++jj) {
            int i = (jj < 4) ? (4 * q + jj) : (16 + 4 * q + (jj - 4));
            int reg = jj & 3;
            float hv = (jj < 4) ? hacc[0][reg] : hacc[1][reg];
            hv = fmaxf(hv + s_hb1[i], 0.0f);
            p0 = fmaf(hv, s_hw2[i], p0);
            p1 = fmaf(hv, s_hw2[32 + i], p1);
        }
        p0 += __shfl_xor(p0, 16);
        p0 += __shfl_xor(p0, 32);
        p1 += __shfl_xor(p1, 16);
        p1 += __shfl_xor(p1, 32);

        float alpha = sigm(p0 + s_hb2[0]);
        float rr = fmaf(0.8f, sigm(p1 + s_hb2[1]), 0.2f);
        float md = __expf(alpha * __logf(mv + 1e-6f));
        float bse = xc / md + 2.0f;
        float val = __expf(rr * __logf(bse)) - __expf(rr * 0.69314718056f);
        if (q == 0 && t < TOUT)
            outb[t] = val;
    }
}

extern "C" void kernel_launch(void* const* d_in, const int* in_sizes, int n_in,
                              void* d_out, int out_size, void* d_ws, size_t ws_size,
                              hipStream_t stream) {
    const float* x    = (const float*)d_in[0];
    const float* cf   = (const float*)d_in[1];
    const float* bw   = (const float*)d_in[2];
    const float* pw   = (const float*)d_in[3];
    const float* w_ih = (const float*)d_in[4];
    const float* w_hh = (const float*)d_in[5];
    const float* b_ih = (const float*)d_in[6];
    const float* b_hh = (const float*)d_in[7];
    const float* hw1  = (const float*)d_in[8];
    const float* hb1  = (const float*)d_in[9];
    const float* hw2  = (const float*)d_in[10];
    const float* hb2  = (const float*)d_in[11];
    float* out = (float*)d_out;

    // tier: batches per conv slice by ws capacity (ws_size constant -> graph-safe)
    const size_t xb_b = (size_t)BB * LST * 2;
    const size_t ag_b = (size_t)80 * AST * 2;
    const size_t wg_b = (size_t)NF * WROW * 4;
    size_t fixed = xb_b + ag_b + wg_b;
    size_t e_per_batch = (size_t)NF * LL * 2 + (size_t)NF * TOUT * 4;
    int nb;
    if (ws_size >= fixed + 8 * e_per_batch)      nb = 8;
    else if (ws_size >= fixed + 2 * e_per_batch) nb = 2;
    else                                         nb = 1;
    int nslice = BB / nb;

    f16* xb     = (f16*)d_ws;                       // [BB][LST]
    f16* Ag     = xb + (size_t)BB * LST;            // [80][AST]
    float* winG = (float*)(Ag + (size_t)80 * AST);  // [NF][WROW]
    f16* ebuf   = (f16*)(winG + (size_t)NF * WROW); // [nb][NF][LL]
    float* Xf   = (float*)(ebuf + (size_t)nb * NF * LL);  // [nb][NF][TOUT]

    prep_all<<<dim3(NCONVB + 80 + NF), dim3(256), 0, stream>>>(x, cf, bw, pw, xb, Ag, winG);

    for (int sl = 0; sl < nslice; ++sl) {
        conv_mfma<<<dim3(NCHUNKC, nb), dim3(256), 0, stream>>>(
            xb + (size_t)sl * nb * LST, Ag, ebuf);
        pool_kernel<<<dim3(NCHUNKP, NF, nb), dim3(256), 0, stream>>>(
            ebuf, winG, Xf);
        scanctrl_kernel<<<dim3(nb * NF), dim3(256), 0, stream>>>(
            Xf, w_ih, w_hh, b_ih, b_hh, hw1, hb1, hw2, hb2,
            out + (size_t)sl * nb * NF * TOUT);
    }
}

// Round 13
// 263.349 us; speedup vs baseline: 1.2723x; 1.0608x over previous
//
#include <hip/hip_runtime.h>
#include <math.h>

#define NF 40
#define FS 401
#define AST 424            // A row stride (f16), 848B, 16B-aligned rows
#define PSTRIDE 160
#define BB 8
#define LL 160000
#define PADL 256
#define LST 161024         // PADL + LL + 768 pad; multiple of 256
#define TOUT 1000
#define NTILE 512          // conv positions per block (4 waves x 128)
#define NCHUNKC 313        // 313*512 = 160256 >= 160000
#define ROWCH 121          // slab chunk stride per row; 121 % 8 == 1
#define ROWST (ROWCH*8)    // 968 f16 per row
#define EROW 520           // e-LDS row stride (f16)
#define WROW 402           // win table row stride (f32), [401]=0
#define TCP 32             // frames per pool block
#define NCHUNKP 32         // 32*32 = 1024 >= 1000
#define PELEM (TCP*PSTRIDE + 408)   // 5528 staged f16 per pool block
#define NCONVB 5032        // BB*LST/256 exactly

typedef __attribute__((ext_vector_type(8))) _Float16 half8v;
typedef __attribute__((ext_vector_type(4))) _Float16 half4v;
typedef __attribute__((ext_vector_type(2))) _Float16 half2v;
typedef __attribute__((ext_vector_type(4))) float float4v;
typedef _Float16 f16;

__device__ __forceinline__ float sigm(float x) { return 1.0f / (1.0f + __expf(-x)); }
__device__ __forceinline__ float tanh_fast(float x) { return 1.0f - 2.0f / (__expf(2.0f * x) + 1.0f); }

// ---------- prep (single dispatch): x->f16 padded, Gabor filters, win table ----------
__global__ __launch_bounds__(256) void prep_all(
    const float* __restrict__ x, const float* __restrict__ cf_,
    const float* __restrict__ bw_, const float* __restrict__ pw_,
    f16* __restrict__ xb, f16* __restrict__ Ag, float* __restrict__ winG)
{
    int blk = blockIdx.x;
    if (blk < NCONVB) {
        int i = blk * 256 + threadIdx.x;
        int b = i / LST, o = i % LST;
        float v = 0.0f;
        if (o >= PADL && o < PADL + LL) v = x[b * LL + (o - PADL)];
        xb[i] = (f16)v;
        return;
    }
    const float PI_F = 3.14159265358979323846f;
    if (blk < NCONVB + 80) {
        int row = blk - NCONVB;
        int f = row >> 1, comp = row & 1;
        float Z = sqrtf(2.0f * logf(2.0f)) / PI_F;
        float cf = fminf(fmaxf(cf_[f], 0.0f), PI_F);
        float bw = fminf(fmaxf(bw_[f], 4.0f * Z), 401.0f * Z);
        float denom = 1.0f / (sqrtf(2.0f * PI_F) * bw);
        float inv2 = 1.0f / (2.0f * bw * bw);
        for (int k = threadIdx.x; k < AST; k += 256) {
            float v = 0.0f;
            if (k < FS) {
                float t = (float)(k - 200);
                float g = denom * expf(-(t * t) * inv2);
                float sv, cv;
                sincosf(cf * t, &sv, &cv);
                v = comp ? g * sv : g * cv;
            }
            Ag[row * AST + k] = (f16)v;
        }
        return;
    }
    int f = blk - NCONVB - 80;
    float pw = fminf(fmaxf(pw_[f], 2.0f / 401.0f), 0.5f);
    float invpw = 1.0f / pw;
    for (int j = threadIdx.x; j < WROW; j += 256) {
        float w = 0.0f;
        if (j < FS) {
            float tt = (float)j * (1.0f / 400.0f) - 0.5f;
            float u = tt * invpw;
            w = expf(-0.5f * u * u);
        }
        winG[f * WROW + j] = w;
    }
}

// ---------- conv via MFMA: N=128/wave + Toeplitz rotation + two-pass coalesced epilogue ----------
__global__ __launch_bounds__(256, 2) void conv_mfma(
    const f16* __restrict__ xb,    // padded [nb][LST]
    const f16* __restrict__ Ag,    // [80][AST]
    f16* __restrict__ eb)          // [nb][NF][LL]
{
    // LDS: slab 15488 B during K-loop; e-tile (max 24 rows x EROW f16 = 24960 B) after
    __shared__ __align__(16) unsigned char smem[24 * EROW * 2];
    f16* slab = (f16*)smem;
    f16* eL   = (f16*)smem;

    int chunk = blockIdx.x;
    int bi = blockIdx.y;
    int p0 = chunk * NTILE;
    int pbase = PADL + p0 - 200;              // ≡ 0 (mod 8)
    const f16* xs = xb + (size_t)bi * LST;
    int tid = threadIdx.x;

    for (int sc = tid; sc < 8 * 120; sc += 256) {
        int r = sc / 120, m = sc - r * 120;
        int s0 = pbase + 8 * m + (r & ~1);
        const uint* gp = (const uint*)(xs + s0);
        uint v0 = gp[0], v1 = gp[1], v2 = gp[2], v3 = gp[3], v4 = gp[4];
        if (r & 1) {
            v0 = __builtin_amdgcn_alignbyte(v1, v0, 2);
            v1 = __builtin_amdgcn_alignbyte(v2, v1, 2);
            v2 = __builtin_amdgcn_alignbyte(v3, v2, 2);
            v3 = __builtin_amdgcn_alignbyte(v4, v3, 2);
        }
        *(uint4*)(&slab[r * ROWST + 8 * m]) = make_uint4(v0, v1, v2, v3);
    }
    __syncthreads();

    int wv = tid >> 6, lane = tid & 63, q = lane >> 4, l15 = lane & 15;

    float4v acc[5][8];
#pragma unroll
    for (int t = 0; t < 5; ++t)
#pragma unroll
        for (int s = 0; s < 8; ++s)
            acc[t][s] = (float4v){0.f, 0.f, 0.f, 0.f};

    const f16* aP[5];
    const f16* bPtr[10];
#pragma unroll
    for (int t = 0; t < 5; ++t) aP[t] = Ag + (16 * t + l15) * AST + 8 * q;
#pragma unroll
    for (int s = 0; s < 10; ++s) {
        int pos = 128 * wv + 16 * s + l15;
        bPtr[s] = slab + (pos & 7) * ROWST + 8 * ((pos >> 3) + q);
    }

    half8v bf[8];
#pragma unroll
    for (int s = 0; s < 8; ++s) bf[s] = *(const half8v*)(bPtr[s]);

#pragma unroll
    for (int kk = 0; kk < 13; ++kk) {
        int k = 32 * kk;
        half8v af[5];
#pragma unroll
        for (int t = 0; t < 5; ++t) af[t] = *(const half8v*)(aP[t] + k);
        half8v nb0, nb1;
        if (kk < 12) {
            nb0 = *(const half8v*)(bPtr[8] + k);
            nb1 = *(const half8v*)(bPtr[9] + k);
        }
#pragma unroll
        for (int t = 0; t < 5; ++t)
#pragma unroll
            for (int s = 0; s < 8; ++s)
                acc[t][s] = __builtin_amdgcn_mfma_f32_16x16x32_f16(af[t], bf[s], acc[t][s], 0, 0, 0);
        if (kk < 12) {
#pragma unroll
            for (int s = 0; s < 6; ++s) bf[s] = bf[s + 2];
            bf[6] = nb0; bf[7] = nb1;
        }
    }

    __syncthreads();   // slab dead; eL overlays

    f16* ebb = eb + (size_t)bi * NF * LL;

    // ---- pass 1: filter rows 0..15 (t = 0,1) ----
#pragma unroll
    for (int t = 0; t < 2; ++t) {
        int f0 = 8 * t + 2 * q;
#pragma unroll
        for (int s = 0; s < 8; ++s) {
            float4v a = acc[t][s];
            int pl = 128 * wv + 16 * s + l15;
            eL[f0 * EROW + pl] = (f16)(a.x * a.x + a.y * a.y);
            eL[(f0 + 1) * EROW + pl] = (f16)(a.z * a.z + a.w * a.w);
        }
    }
    __syncthreads();
#pragma unroll
    for (int it = 0; it < 4; ++it) {
        int idx = it * 256 + tid;
        int row = idx >> 6;                   // 0..15
        int off = (idx & 63) * 8;
        if (p0 + off < LL) {
            uint4 v = *(const uint4*)(&eL[row * EROW + off]);
            *(uint4*)(&ebb[row * LL + p0 + off]) = v;
        }
    }
    __syncthreads();

    // ---- pass 2: filter rows 16..39 (t = 2,3,4) ----
#pragma unroll
    for (int t = 2; t < 5; ++t) {
        int f0 = 8 * t + 2 * q;
#pragma unroll
        for (int s = 0; s < 8; ++s) {
            float4v a = acc[t][s];
            int pl = 128 * wv + 16 * s + l15;
            eL[(f0 - 16) * EROW + pl] = (f16)(a.x * a.x + a.y * a.y);
            eL[(f0 - 15) * EROW + pl] = (f16)(a.z * a.z + a.w * a.w);
        }
    }
    __syncthreads();
#pragma unroll
    for (int it = 0; it < 6; ++it) {
        int idx = it * 256 + tid;
        int row = idx >> 6;                   // 0..23
        int off = (idx & 63) * 8;
        if (p0 + off < LL) {
            uint4 v = *(const uint4*)(&eL[row * EROW + off]);
            *(uint4*)(&ebb[(row + 16) * LL + p0 + off]) = v;
        }
    }
}

// ---------- Gaussian pooling v2: f16 LDS staging, precomputed win ----------
__global__ __launch_bounds__(256) void pool_kernel(
    const f16* __restrict__ eb, const float* __restrict__ winG, float* __restrict__ Xout)
{
    __shared__ __align__(16) f16 es[PELEM + 8];
    __shared__ __align__(16) float win[416];
    int chunk = blockIdx.x;
    int f = blockIdx.y;
    int bi = blockIdx.z;
    int tau0 = chunk * TCP;
    int start = tau0 * PSTRIDE - 200;               // ≡ 0 (mod 8)
    int tid = threadIdx.x;

    for (int k = tid; k < 416; k += 256)
        win[k] = (k < WROW) ? winG[f * WROW + k] : 0.0f;

    const f16* erow = eb + ((size_t)bi * NF + f) * LL;
    if (start >= 0 && start + PELEM <= LL) {
        for (int j = tid; j < PELEM / 8; j += 256)
            *(uint4*)(&es[8 * j]) = *(const uint4*)(erow + start + 8 * j);
    } else {
        for (int j = tid; j < PELEM; j += 256) {
            int p = start + j;
            es[j] = (p >= 0 && p < LL) ? erow[p] : (f16)0.0f;
        }
    }
    __syncthreads();

    int ft = tid >> 4, l16 = tid & 15;
#pragma unroll
    for (int pass = 0; pass < 2; ++pass) {
        int frame = pass * 16 + ft;
        int base = frame * PSTRIDE;
        float acc = 0.0f;
#pragma unroll
        for (int m = 0; m < 13; ++m) {
            int kw = 2 * l16 + 32 * m;
            half2v ep = *(const half2v*)(&es[base + kw]);
            float2 wp = *(const float2*)(&win[kw]);
            acc = fmaf((float)ep[0], wp.x, acc);
            acc = fmaf((float)ep[1], wp.y, acc);
        }
#pragma unroll
        for (int off = 8; off > 0; off >>= 1)
            acc += __shfl_down(acc, off, 16);
        int tau = tau0 + frame;
        if (l16 == 0 && tau < TOUT)
            Xout[((size_t)bi * NF + f) * TOUT + tau] = acc;
    }
}

// ---------- PCEN smoother M via wave-per-bin decayed scan ----------
__global__ __launch_bounds__(256) void pcen_scan_kernel(
    const float* __restrict__ X, float* __restrict__ M)
{
    int wid = (blockIdx.x * 256 + threadIdx.x) >> 6;
    int lane = threadIdx.x & 63;
    if (wid >= BB * NF) return;
    const float a1 = 0.96f;
    const float a2 = a1 * a1;
    const float a4 = a2 * a2;
    const float a8 = a4 * a4;
    const float a16 = a8 * a8;
    const float a32 = a16 * a16;
    const float ss = 0.04f;
    float al1 = powf(a1, (float)(lane + 1));
    float carry = 0.0f;
    const float* row = X + wid * TOUT;
    float* mrow = M + wid * TOUT;

    for (int c = 0; c < TOUT; c += 64) {
        int t = c + lane;
        float v = (t < TOUT) ? row[t] : 0.0f;
        float y = ss * v;
        float u;
        u = __shfl_up(y, 1, 64);  if (lane >= 1)  y = fmaf(a1, u, y);
        u = __shfl_up(y, 2, 64);  if (lane >= 2)  y = fmaf(a2, u, y);
        u = __shfl_up(y, 4, 64);  if (lane >= 4)  y = fmaf(a4, u, y);
        u = __shfl_up(y, 8, 64);  if (lane >= 8)  y = fmaf(a8, u, y);
        u = __shfl_up(y, 16, 64); if (lane >= 16) y = fmaf(a16, u, y);
        u = __shfl_up(y, 32, 64); if (lane >= 32) y = fmaf(a32, u, y);
        y = fmaf(al1, carry, y);
        carry = __shfl(y, 63, 64);
        if (t < TOUT) mrow[t] = y;
    }
}

// ---------- GRU controller + PCEN via MFMA (C-layout gates), grid 5000 ----------
__global__ __launch_bounds__(256) void pcen_ctrl_mfma(
    const float* __restrict__ X, const float* __restrict__ M,
    const float* __restrict__ w_ih, const float* __restrict__ w_hh,
    const float* __restrict__ b_ih, const float* __restrict__ b_hh,
    const float* __restrict__ hw1, const float* __restrict__ hb1,
    const float* __restrict__ hw2, const float* __restrict__ hb2,
    float* __restrict__ out)
{
    __shared__ f16 s_whhA[96 * 40];
    __shared__ f16 s_w1A[32 * 40];
    __shared__ __align__(16) float4 s_A1[32];
    __shared__ __align__(16) float4 s_A2[32];
    __shared__ float s_hb1[32];
    __shared__ float s_hw2[64];
    __shared__ float s_hb2[2];
    __shared__ f16 sh1[4][16 * 40];
    __shared__ f16 sh2[4][16 * 40];

    int tid = threadIdx.x;
    for (int i = tid; i < 96 * 32; i += 256) {
        int m = i >> 5, k = i & 31;
        s_whhA[m * 40 + k] = (f16)w_hh[i];
    }
    for (int i = tid; i < 32 * 32; i += 256) {
        int m = i >> 5, k = i & 31;
        s_w1A[m * 40 + k] = (f16)hw1[i];
    }
    if (tid < 32) {
        int j = tid;
        s_A1[j] = make_float4(w_ih[j], b_ih[j] + b_hh[j],
                              w_ih[32 + j], b_ih[32 + j] + b_hh[32 + j]);
        s_A2[j] = make_float4(w_ih[64 + j], b_ih[64 + j], b_hh[64 + j], 0.0f);
        s_hb1[j] = hb1[j];
    }
    if (tid < 64) s_hw2[tid] = hw2[tid];
    if (tid < 2)  s_hb2[tid] = hb2[tid];
    __syncthreads();

    int wv = tid >> 6, lane = tid & 63;
    int c = lane & 15, q = lane >> 4;
    int instBase = blockIdx.x * 64 + wv * 16;

    // direct per-lane loads (quad-redundant, L1-broadcast) — no LDS bounce
    int idx = instBase + c;
    int t = idx % TOUT;
    float xc = X[idx];
    float xp = (t == 0) ? xc : X[idx - 1];
    float mv = M[idx];

    float h1v[8];
#pragma unroll
    for (int jj = 0; jj < 8; ++jj) {
        int j = (jj < 4) ? (4 * q + jj) : (16 + 4 * q + (jj - 4));
        float4 a1 = s_A1[j];
        float4 a2 = s_A2[j];
        float r = sigm(fmaf(xp, a1.x, a1.y));
        float z = sigm(fmaf(xp, a1.z, a1.w));
        float n = tanh_fast(fmaf(xp, a2.x, a2.y) + r * a2.z);
        h1v[jj] = (1.0f - z) * n;
    }

    {
        half4v lo = {(f16)h1v[0], (f16)h1v[1], (f16)h1v[2], (f16)h1v[3]};
        half4v hi = {(f16)h1v[4], (f16)h1v[5], (f16)h1v[6], (f16)h1v[7]};
        *(half4v*)(&sh1[wv][c * 40 + 4 * q]) = lo;
        *(half4v*)(&sh1[wv][c * 40 + 16 + 4 * q]) = hi;
    }

    float4v acc[6];
    {
        half8v bf = *(const half8v*)(&sh1[wv][c * 40 + 8 * q]);
#pragma unroll
        for (int tt = 0; tt < 6; ++tt) {
            half8v af = *(const half8v*)(&s_whhA[(16 * tt + c) * 40 + 8 * q]);
            acc[tt] = __builtin_amdgcn_mfma_f32_16x16x32_f16(af, bf, (float4v){0.f,0.f,0.f,0.f}, 0, 0, 0);
        }
    }

    float h2v[8];
#pragma unroll
    for (int jj = 0; jj < 8; ++jj) {
        int j = (jj < 4) ? (4 * q + jj) : (16 + 4 * q + (jj - 4));
        int reg = jj & 3;
        float accR = (jj < 4) ? acc[0][reg] : acc[1][reg];
        float accZ = (jj < 4) ? acc[2][reg] : acc[3][reg];
        float accN = (jj < 4) ? acc[4][reg] : acc[5][reg];
        float4 a1 = s_A1[j];
        float4 a2 = s_A2[j];
        float r = sigm(fmaf(xc, a1.x, a1.y) + accR);
        float z = sigm(fmaf(xc, a1.z, a1.w) + accZ);
        float gn = accN + a2.z;
        float n = tanh_fast(fmaf(xc, a2.x, a2.y) + r * gn);
        h2v[jj] = fmaf(z, h1v[jj] - n, n);
    }

    {
        half4v lo = {(f16)h2v[0], (f16)h2v[1], (f16)h2v[2], (f16)h2v[3]};
        half4v hi = {(f16)h2v[4], (f16)h2v[5], (f16)h2v[6], (f16)h2v[7]};
        *(half4v*)(&sh2[wv][c * 40 + 4 * q]) = lo;
        *(half4v*)(&sh2[wv][c * 40 + 16 + 4 * q]) = hi;
    }

    float4v hacc[2];
    {
        half8v bf = *(const half8v*)(&sh2[wv][c * 40 + 8 * q]);
#pragma unroll
        for (int tt = 0; tt < 2; ++tt) {
            half8v af = *(const half8v*)(&s_w1A[(16 * tt + c) * 40 + 8 * q]);
            hacc[tt] = __builtin_amdgcn_mfma_f32_16x16x32_f16(af, bf, (float4v){0.f,0.f,0.f,0.f}, 0, 0, 0);
        }
    }

    float p0 = 0.f, p1 = 0.f;
#pragma unroll
    for (int jj = 0; jj < 8; ++jj) {
        int i = (jj < 4) ? (4 * q + jj) : (16 + 4 * q + (jj - 4));
        int reg = jj & 3;
        float hv = (jj < 4) ? hacc[0][reg] : hacc[1][reg];
        hv = fmaxf(hv + s_hb1[i], 0.0f);
        p0 = fmaf(hv, s_hw2[i], p0);
        p1 = fmaf(hv, s_hw2[32 + i], p1);
    }
    p0 += __shfl_xor(p0, 16);
    p0 += __shfl_xor(p0, 32);
    p1 += __shfl_xor(p1, 16);
    p1 += __shfl_xor(p1, 32);

    float alpha = sigm(p0 + s_hb2[0]);
    float rr = fmaf(0.8f, sigm(p1 + s_hb2[1]), 0.2f);
    float md = __expf(alpha * __logf(mv + 1e-6f));
    float bse = xc / md + 2.0f;
    float val = __expf(rr * __logf(bse)) - __expf(rr * 0.69314718056f);
    if (lane < 16)
        out[idx] = val;
}

extern "C" void kernel_launch(void* const* d_in, const int* in_sizes, int n_in,
                              void* d_out, int out_size, void* d_ws, size_t ws_size,
                              hipStream_t stream) {
    const float* x    = (const float*)d_in[0];
    const float* cf   = (const float*)d_in[1];
    const float* bw   = (const float*)d_in[2];
    const float* pw   = (const float*)d_in[3];
    const float* w_ih = (const float*)d_in[4];
    const float* w_hh = (const float*)d_in[5];
    const float* b_ih = (const float*)d_in[6];
    const float* b_hh = (const float*)d_in[7];
    const float* hw1  = (const float*)d_in[8];
    const float* hb1  = (const float*)d_in[9];
    const float* hw2  = (const float*)d_in[10];
    const float* hb2  = (const float*)d_in[11];
    float* out = (float*)d_out;

    // tier: batches per conv slice by ws capacity (ws_size constant -> graph-safe)
    const size_t xb_b = (size_t)BB * LST * 2;
    const size_t ag_b = (size_t)80 * AST * 2;
    const size_t wg_b = (size_t)NF * WROW * 4;
    const size_t xm_b = (size_t)2 * BB * NF * TOUT * 4;
    size_t fixed = xb_b + ag_b + wg_b + xm_b;
    size_t e_per_batch = (size_t)NF * LL * 2;
    int nb;
    if (ws_size >= fixed + 8 * e_per_batch)      nb = 8;
    else if (ws_size >= fixed + 2 * e_per_batch) nb = 2;
    else                                         nb = 1;
    int nslice = BB / nb;

    f16* xb     = (f16*)d_ws;                       // [BB][LST]
    f16* Ag     = xb + (size_t)BB * LST;            // [80][AST]
    float* winG = (float*)(Ag + (size_t)80 * AST);  // [NF][WROW]
    f16* ebuf   = (f16*)(winG + (size_t)NF * WROW); // [nb][NF][LL]
    float* Xf   = (float*)(ebuf + (size_t)nb * NF * LL);  // [BB][NF][TOUT]
    float* Mf   = Xf + (size_t)BB * NF * TOUT;

    prep_all<<<dim3(NCONVB + 80 + NF), dim3(256), 0, stream>>>(x, cf, bw, pw, xb, Ag, winG);

    for (int sl = 0; sl < nslice; ++sl) {
        conv_mfma<<<dim3(NCHUNKC, nb), dim3(256), 0, stream>>>(
            xb + (size_t)sl * nb * LST, Ag, ebuf);
        pool_kernel<<<dim3(NCHUNKP, NF, nb), dim3(256), 0, stream>>>(
            ebuf, winG, Xf + (size_t)sl * nb * NF * TOUT);
    }

    pcen_scan_kernel<<<dim3((BB * NF * 64) / 256), dim3(256), 0, stream>>>(Xf, Mf);
    pcen_ctrl_mfma<<<dim3((BB * NF * TOUT) / 64), dim3(256), 0, stream>>>(
        Xf, Mf, w_ih, w_hh, b_ih, b_hh, hw1, hb1, hw2, hb2, out);
}